// Round 1
// baseline (200.174 us; speedup 1.0000x reference)
//
#include <hip/hip_runtime.h>
#include <math.h>

#define B_N 32768
#define NCLS 1000
#define NSAMP 1000000
#define NTAB 31

__constant__ float c_conf[NTAB] = {
    0.9991138577461243f, 0.8724386692047119f, 0.8048540353775024f, 0.7398145198822021f,
    0.6715637445449829f, 0.5973713397979736f, 0.5154045820236206f, 0.42423248291015625f,
    0.3226756751537323f, 0.20976418256759644f, 0.08473344892263412f, -0.05296758562326431f,
    -0.2036692053079605f, -0.3674810528755188f, -0.5443023443222046f, -0.7338425517082214f,
    -0.9356498718261719f, -1.149145483970642f, -1.3736592531204224f, -1.6084641218185425f,
    -1.8528070449829102f, -2.1059343814849854f, -2.367111921310425f, -2.6356399059295654f,
    -2.910861015319824f, -3.1921679973602295f, -3.479003667831421f, -3.770861864089966f,
    -4.067285060882568f, -4.367861747741699f, -4.67222261428833f};

// Precomputed from the LOSS_DIV_WD table:
//   LOG0 = ln(-0.7357585932962737 + 0.750256) = -4.23378549
//   LOG30 = ln(999.249744 + 0.750256) = ln(1000) = 6.90775528
//   LOG_STEP = (LOG30-LOG0)/2 = 5.57077038 ; LOG_OFFSET = LOG0+LOG_STEP = 1.33698489
#define LOG_OFFSET 1.3369849f
#define INV_LOG_STEP 0.17950834f
#define LN_SMOOTH -0.10536052f  /* ln(0.9) */

__device__ __forceinline__ float optimal_conf(float l) {
    float ln = (logf(l + 0.750256f) - LOG_OFFSET) * INV_LOG_STEP;
    if (ln != ln) ln = -1.0f;                       // NaN (log of negative) -> left border
    float ix = fminf(fmaxf((ln + 1.0f) * 0.5f * (NTAB - 1), 0.0f), (float)(NTAB - 1));
    float i0f = floorf(ix);
    float frac = ix - i0f;
    int i0 = (int)i0f;
    int i1 = min(i0 + 1, NTAB - 1);
    float r = c_conf[i0] * (1.0f - frac) + c_conf[i1] * frac;
    return expf(r);
}

// One block per row: CE loss + atomic bin accumulation.
__global__ __launch_bounds__(256) void ce_loss_kernel(
    const float* __restrict__ preds, const int* __restrict__ labels,
    const int* __restrict__ indices, float* __restrict__ loss,
    float* __restrict__ ins_sum, float* __restrict__ ins_cnt,
    float* __restrict__ cls_sum, float* __restrict__ cls_cnt)
{
    const int row = blockIdx.x;
    const int t = threadIdx.x;
    const float4* p = (const float4*)(preds + (size_t)row * NCLS);

    float4 v = make_float4(-INFINITY, -INFINITY, -INFINITY, -INFINITY);
    if (t < NCLS / 4) v = p[t];

    // block max
    float m = fmaxf(fmaxf(v.x, v.y), fmaxf(v.z, v.w));
    #pragma unroll
    for (int off = 32; off > 0; off >>= 1) m = fmaxf(m, __shfl_down(m, off, 64));
    __shared__ float sm[4];
    __shared__ float bcast;
    const int wave = t >> 6, lane = t & 63;
    if (lane == 0) sm[wave] = m;
    __syncthreads();
    if (t == 0) bcast = fmaxf(fmaxf(sm[0], sm[1]), fmaxf(sm[2], sm[3]));
    __syncthreads();
    const float M = bcast;

    // block sum of exp(x - M)
    float s = 0.0f;
    if (t < NCLS / 4)
        s = expf(v.x - M) + expf(v.y - M) + expf(v.z - M) + expf(v.w - M);
    #pragma unroll
    for (int off = 32; off > 0; off >>= 1) s += __shfl_down(s, off, 64);
    __syncthreads();
    if (lane == 0) sm[wave] = s;
    __syncthreads();

    if (t == 0) {
        const float S = sm[0] + sm[1] + sm[2] + sm[3];
        const int lab = labels[row];
        const float l = logf(S) + M - preds[(size_t)row * NCLS + lab];
        loss[row] = l;
        const int idx = indices[row];
        atomicAdd(&ins_sum[idx], l);
        atomicAdd(&ins_cnt[idx], 1.0f);
        atomicAdd(&cls_sum[lab], l);
        atomicAdd(&cls_cnt[lab], 1.0f);
    }
}

// Per-sample EMA + conf interp + mean reduction.
__global__ __launch_bounds__(256) void conf_reduce_kernel(
    const float* __restrict__ loss, const int* __restrict__ labels,
    const int* __restrict__ indices,
    const float* __restrict__ mem_ins, const float* __restrict__ mem_cls,
    const float* __restrict__ ins_sum, const float* __restrict__ ins_cnt,
    const float* __restrict__ cls_sum, const float* __restrict__ cls_cnt,
    float* __restrict__ out)
{
    const int i = blockIdx.x * 256 + threadIdx.x;
    float val = 0.0f;
    if (i < B_N) {
        const float l = loss[i];
        const int idx = indices[i];
        const int lab = labels[i];

        const float ci = ins_cnt[idx];                 // >= 1 for gathered bins
        const float mean_i = ins_sum[idx] / ci;
        const float ai = expf(ci * LN_SMOOTH);         // 0.9^cnt
        const float sl_i = ai * mem_ins[idx] + (1.0f - ai) * mean_i;

        const float cc = cls_cnt[lab];
        const float mean_c = cls_sum[lab] / cc;
        const float ac = expf(cc * LN_SMOOTH);
        const float sl_c = ac * mem_cls[lab] + (1.0f - ac) * mean_c;

        const float conf = optimal_conf(sl_i) * optimal_conf(sl_c);
        val = l * conf * (1.0f / (float)B_N);
    }
    #pragma unroll
    for (int off = 32; off > 0; off >>= 1) val += __shfl_down(val, off, 64);
    __shared__ float sm[4];
    const int wave = threadIdx.x >> 6, lane = threadIdx.x & 63;
    if (lane == 0) sm[wave] = val;
    __syncthreads();
    if (threadIdx.x == 0) atomicAdd(out, sm[0] + sm[1] + sm[2] + sm[3]);
}

extern "C" void kernel_launch(void* const* d_in, const int* in_sizes, int n_in,
                              void* d_out, int out_size, void* d_ws, size_t ws_size,
                              hipStream_t stream) {
    const float* preds   = (const float*)d_in[0];
    const float* mem_ins = (const float*)d_in[1];
    const float* mem_cls = (const float*)d_in[2];
    const int*   labels  = (const int*)d_in[3];
    const int*   indices = (const int*)d_in[4];
    float* out = (float*)d_out;

    float* loss    = (float*)d_ws;            // B_N
    float* ins_sum = loss + B_N;              // NSAMP
    float* ins_cnt = ins_sum + NSAMP;         // NSAMP
    float* cls_sum = ins_cnt + NSAMP;         // NCLS
    float* cls_cnt = cls_sum + NCLS;          // NCLS

    // zero the contiguous bin-aggregate region + the scalar output
    hipMemsetAsync(ins_sum, 0, (size_t)(2 * NSAMP + 2 * NCLS) * sizeof(float), stream);
    hipMemsetAsync(out, 0, sizeof(float), stream);

    ce_loss_kernel<<<B_N, 256, 0, stream>>>(preds, labels, indices, loss,
                                            ins_sum, ins_cnt, cls_sum, cls_cnt);
    conf_reduce_kernel<<<(B_N + 255) / 256, 256, 0, stream>>>(
        loss, labels, indices, mem_ins, mem_cls,
        ins_sum, ins_cnt, cls_sum, cls_cnt, out);
}